// Round 4
// baseline (150.127 us; speedup 1.0000x reference)
//
#include <hip/hip_runtime.h>
#include <hip/hip_bf16.h>
#include <cstdint>

#define NN 100000
#define DEG 16
#define FF 256
#define UU 128
#define SLICE_BYTES 3200000  // NN * 16 dims * 2B

typedef __attribute__((ext_vector_type(8))) short short8;
typedef __attribute__((ext_vector_type(4))) float f32x4;

__device__ __forceinline__ unsigned short f2bf(float x) {
    uint32_t u = __builtin_bit_cast(uint32_t, x);
    uint32_t r = (u + 0x7fffu + ((u >> 16) & 1u)) >> 16;
    return (unsigned short)r;
}
__device__ __forceinline__ float bf2f(unsigned short b) {
    return __builtin_bit_cast(float, (uint32_t)b << 16);
}

// Pre-kernel: W [256][128] f32 -> Wt [128][256] bf16 (transposed, 64 KB, L2-hot).
__global__ void k_convW(const float* __restrict__ W, unsigned short* __restrict__ Wt) {
    int i = blockIdx.x * 256 + threadIdx.x;  // 32768 elements
    int k = i >> 7, c = i & 127;
    Wt[c * 256 + k] = f2bf(W[i]);
}

// GEMM: h = ns @ W via bf16 MFMA. Block = 64 rows x 128 cols, 4 waves,
// wave w owns cols [w*32, w*32+32). A staged fp32->bf16 into XOR-swizzled LDS.
// B fragments PINNED in registers via empty asm (round-2/3 post-mortem: the
// compiler sank them into the K-loop -> 16 extra VMEM loads per ks).
// Epilogue: LDS roundtrip -> slice-major hb_s store + fused attention dots.
__global__ __launch_bounds__(256, 2) void k_gemm(
    const float* __restrict__ ns, const unsigned short* __restrict__ Wt,
    const float* __restrict__ ka, unsigned short* __restrict__ hbs,
    float* __restrict__ a_src, float* __restrict__ a_dst)
{
    __shared__ char smem[64 * 512 + 1024];  // 32 KB A-tile (reused as Ht) + 1 KB ka
    float* ka_s = (float*)(smem + 64 * 512);
    const int t = threadIdx.x;
    const int lane = t & 63;
    const int w = t >> 6;
    const int row0 = blockIdx.x * 64;
    const int lrow = lane & 15;
    const int khalf = lane >> 4;

    ka_s[t] = ka[t];

    // ---- B fragments: bfrag[nt][ks], (lane,elem)->k = khalf*8 + ks*32 + e ----
    short8 bfrag[2][8];
    {
        const int col0 = w * 32 + lrow;
        #pragma unroll
        for (int nt = 0; nt < 2; ++nt) {
            const unsigned short* wp = Wt + (size_t)(col0 + nt * 16) * 256 + khalf * 8;
            #pragma unroll
            for (int ks = 0; ks < 8; ++ks)
                bfrag[nt][ks] = *(const short8*)(wp + ks * 32);
        }
    }
    // Pin: opaque asm makes rematerialization impossible -> values stay in VGPRs.
    #pragma unroll
    for (int nt = 0; nt < 2; ++nt)
        #pragma unroll
        for (int ks = 0; ks < 8; ++ks)
            asm volatile("" : "+v"(bfrag[nt][ks]));

    // ---- Stage A: 64x256 fp32 -> bf16 LDS, byte ^= (row&7)<<4 swizzle ----
    #pragma unroll
    for (int i = 0; i < 8; ++i) {
        int u = i * 256 + t;
        int row = u >> 5, c8 = u & 31;
        int gr = row0 + row;
        float4 x0, x1;
        if (gr < NN) {
            const float* gp = ns + (size_t)gr * FF + c8 * 8;
            x0 = *(const float4*)gp;
            x1 = *(const float4*)(gp + 4);
        } else {
            x0 = make_float4(0.f, 0.f, 0.f, 0.f);
            x1 = x0;
        }
        short8 v;
        v[0] = f2bf(x0.x); v[1] = f2bf(x0.y); v[2] = f2bf(x0.z); v[3] = f2bf(x0.w);
        v[4] = f2bf(x1.x); v[5] = f2bf(x1.y); v[6] = f2bf(x1.z); v[7] = f2bf(x1.w);
        int byte = (row * 512 + c8 * 16) ^ ((row & 7) << 4);
        *(short8*)(smem + byte) = v;
    }
    __syncthreads();

    // ---- K-loop: 8 ksteps x (4 ds_read_b128 + 8 MFMA), no VMEM inside ----
    f32x4 acc[4][2];
    #pragma unroll
    for (int mt = 0; mt < 4; ++mt)
        #pragma unroll
        for (int nt = 0; nt < 2; ++nt)
            acc[mt][nt] = (f32x4){0.f, 0.f, 0.f, 0.f};

    #pragma unroll
    for (int ks = 0; ks < 8; ++ks) {
        short8 a[4];
        #pragma unroll
        for (int mt = 0; mt < 4; ++mt) {
            int row = mt * 16 + lrow;
            int byte = (row * 512 + ks * 64 + khalf * 16) ^ ((row & 7) << 4);
            a[mt] = *(const short8*)(smem + byte);
        }
        #pragma unroll
        for (int mt = 0; mt < 4; ++mt)
            #pragma unroll
            for (int nt = 0; nt < 2; ++nt)
                acc[mt][nt] = __builtin_amdgcn_mfma_f32_16x16x32_bf16(
                    a[mt], bfrag[nt][ks], acc[mt][nt], 0, 0, 0);
    }

    __syncthreads();  // A-tile reads done; reuse smem as Ht[64][136] ushort

    // ---- acc -> Ht (row stride 136 shorts breaks bank aliasing) ----
    unsigned short* Hs = (unsigned short*)smem;
    {
        const int wcol = w * 32;
        #pragma unroll
        for (int mt = 0; mt < 4; ++mt)
            #pragma unroll
            for (int nt = 0; nt < 2; ++nt)
                #pragma unroll
                for (int r = 0; r < 4; ++r) {
                    int row = mt * 16 + khalf * 4 + r;
                    int col = wcol + nt * 16 + lrow;
                    Hs[row * 136 + col] = f2bf(acc[mt][nt][r]);
                }
    }
    __syncthreads();

    // ---- slice-major hb_s store + attention dots (4 threads per row) ----
    {
        int row = t >> 2, q = t & 3;
        int gr = row0 + row;
        float ps = 0.f, pd = 0.f;
        short8 hv[4];
        #pragma unroll
        for (int j = 0; j < 4; ++j) {
            hv[j] = *(const short8*)(Hs + row * 136 + q * 32 + j * 8);
            #pragma unroll
            for (int e = 0; e < 8; ++e) {
                float hf = bf2f((unsigned short)hv[j][e]);
                int c = q * 32 + j * 8 + e;
                ps = fmaf(hf, ka_s[c], ps);
                pd = fmaf(hf, ka_s[UU + c], pd);
            }
        }
        if (gr < NN) {
            // cols q*32..q*32+31 = slices 2q (dims 0-15) and 2q+1 (dims 16-31)
            char* base = (char*)hbs + (size_t)(2 * q) * SLICE_BYTES + (size_t)gr * 32;
            *(short8*)(base) = hv[0];
            *(short8*)(base + 16) = hv[1];
            *(short8*)(base + SLICE_BYTES) = hv[2];
            *(short8*)(base + SLICE_BYTES + 16) = hv[3];
        }
        ps += __shfl_xor(ps, 1, 64); ps += __shfl_xor(ps, 2, 64);
        pd += __shfl_xor(pd, 1, 64); pd += __shfl_xor(pd, 2, 64);
        if (q == 0 && gr < NN) { a_src[gr] = ps; a_dst[gr] = pd; }
    }
}

// Edge kernel: scores + per-node softmax -> packed nd[e] = (dst<<15) | norm_q15.
// 16 consecutive threads = one node (src sorted, exactly DEG=16 edges/node).
__global__ __launch_bounds__(256, 8) void k_edge(
    const int* __restrict__ edges, const float* __restrict__ ew,
    const float* __restrict__ a_src, const float* __restrict__ a_dst,
    uint32_t* __restrict__ nd)
{
    const int ei = blockIdx.x * 256 + threadIdx.x;
    const int n = ei >> 4;
    const int dst = edges[2 * ei + 1];
    const float w = ew[ei];
    const float x0 = w * (a_src[n] + a_dst[dst]);
    float x = x0 > 0.f ? x0 : 0.2f * x0;        // leaky_relu, slope 0.2
    x = fminf(2.f, fmaxf(-2.f, x));             // clip
    const float s = __expf(x);

    float ssum = s;                              // xor masks <16 stay in-group
    ssum += __shfl_xor(ssum, 1, 64);
    ssum += __shfl_xor(ssum, 2, 64);
    ssum += __shfl_xor(ssum, 4, 64);
    ssum += __shfl_xor(ssum, 8, 64);
    const float norm = s / ssum;

    uint32_t q15 = (uint32_t)(norm * 32768.f + 0.5f);
    if (q15 > 32767u) q15 = 32767u;
    nd[ei] = ((uint32_t)dst << 15) | q15;
}

// Slice kernel: grid is slice-major (8 slices x 1563 node-blocks). Slice s
// gathers only hb_s[s] (3.2 MB -> XCD-L2 resident). 4 lanes per node, each
// lane owns 4 dims; decoded (dstByte, norm) pairs broadcast via LDS.
__global__ __launch_bounds__(256, 8) void k_slice(
    const uint32_t* __restrict__ nd, const unsigned short* __restrict__ hbs,
    float* __restrict__ out)
{
    __shared__ uint32_t lds[4][16][34];  // [wave][node][16 pairs + pad]
    const int t = threadIdx.x;
    const int wv = t >> 6;
    const int lane = t & 63;
    const int slice = blockIdx.x / 1563;
    const int nb = blockIdx.x % 1563;
    const int nloc = lane >> 2;   // node within wave (16/wave)
    const int sub = lane & 3;     // dim quad within slice
    const int n = nb * 64 + wv * 16 + nloc;
    const bool valid = n < NN;
    const int nc = valid ? n : NN - 1;

    // load + decode this lane's 4 edges (all belong to node nc)
    const uint4 ndv = *(const uint4*)(nd + (size_t)nc * DEG + sub * 4);
    uint32_t* p = &lds[wv][nloc][sub * 8];
    {
        uint32_t d0 = (ndv.x >> 15) << 5, d1 = (ndv.y >> 15) << 5;
        uint32_t d2 = (ndv.z >> 15) << 5, d3 = (ndv.w >> 15) << 5;
        float n0 = (float)(ndv.x & 32767u) * (1.f / 32768.f);
        float n1 = (float)(ndv.y & 32767u) * (1.f / 32768.f);
        float n2 = (float)(ndv.z & 32767u) * (1.f / 32768.f);
        float n3 = (float)(ndv.w & 32767u) * (1.f / 32768.f);
        p[0] = d0; p[1] = __builtin_bit_cast(uint32_t, n0);
        p[2] = d1; p[3] = __builtin_bit_cast(uint32_t, n1);
        p[4] = d2; p[5] = __builtin_bit_cast(uint32_t, n2);
        p[6] = d3; p[7] = __builtin_bit_cast(uint32_t, n3);
    }
    __syncthreads();

    const char* hsbase = (const char*)hbs + (size_t)slice * SLICE_BYTES + sub * 8;
    const uint32_t* ndp = &lds[wv][nloc][0];
    float acc0 = 0.f, acc1 = 0.f, acc2 = 0.f, acc3 = 0.f;
    #pragma unroll
    for (int j = 0; j < 16; ++j) {
        const uint32_t dstB = ndp[j * 2];
        const float normj = __builtin_bit_cast(float, ndp[j * 2 + 1]);
        const uint2 hv = *(const uint2*)(hsbase + dstB);
        acc0 = fmaf(normj, __builtin_bit_cast(float, hv.x << 16), acc0);
        acc1 = fmaf(normj, __builtin_bit_cast(float, hv.x & 0xffff0000u), acc1);
        acc2 = fmaf(normj, __builtin_bit_cast(float, hv.y << 16), acc2);
        acc3 = fmaf(normj, __builtin_bit_cast(float, hv.y & 0xffff0000u), acc3);
    }
    if (valid) {
        float4 o;
        o.x = acc0; o.y = acc1; o.z = acc2; o.w = acc3;
        *(float4*)(out + (size_t)n * UU + slice * 16 + sub * 4) = o;
    }
}

extern "C" void kernel_launch(void* const* d_in, const int* in_sizes, int n_in,
                              void* d_out, int out_size, void* d_ws, size_t ws_size,
                              hipStream_t stream) {
    const float* ns    = (const float*)d_in[0];  // [1, N, 256] f32
    const int*   edges = (const int*)d_in[1];    // [1, E, 2] i32, src sorted
    const float* ew    = (const float*)d_in[2];  // [1, E] f32
    const float* W     = (const float*)d_in[3];  // [256, 128] f32
    const float* ka    = (const float*)d_in[4];  // [256, 1] f32
    float* out = (float*)d_out;                  // [N, 128] f32

    char* ws = (char*)d_ws;
    unsigned short* hbs = (unsigned short*)ws;                   // 8 x 3.2 MB slice-major
    float* a_src = (float*)(ws + (size_t)8 * SLICE_BYTES);       // N f32
    float* a_dst = a_src + NN;                                   // N f32
    unsigned short* Wt = (unsigned short*)(ws + (size_t)8 * SLICE_BYTES + 2 * (size_t)NN * 4);  // 64 KB
    uint32_t* nd = (uint32_t*)(ws + (size_t)8 * SLICE_BYTES + 2 * (size_t)NN * 4 + 65536);      // E u32 = 6.4 MB

    k_convW<<<FF * UU / 256, 256, 0, stream>>>(W, Wt);                         // 128 blocks
    k_gemm<<<(NN + 63) / 64, 256, 0, stream>>>(ns, Wt, ka, hbs, a_src, a_dst); // 1563 blocks
    k_edge<<<NN * DEG / 256, 256, 0, stream>>>(edges, ew, a_src, a_dst, nd);   // 6250 blocks
    k_slice<<<8 * 1563, 256, 0, stream>>>(nd, hbs, out);                       // 12504 blocks
}

// Round 5
// 112.622 us; speedup vs baseline: 1.3330x; 1.3330x over previous
//
#include <hip/hip_runtime.h>
#include <hip/hip_bf16.h>
#include <cstdint>

#define NN 100000
#define DEG 16
#define FF 256
#define UU 128

typedef __attribute__((ext_vector_type(8))) short short8;
typedef __attribute__((ext_vector_type(4))) float f32x4;

__device__ __forceinline__ unsigned short f2bf(float x) {
    uint32_t u = __builtin_bit_cast(uint32_t, x);
    uint32_t r = (u + 0x7fffu + ((u >> 16) & 1u)) >> 16;
    return (unsigned short)r;
}
__device__ __forceinline__ float bf2f(unsigned short b) {
    return __builtin_bit_cast(float, (uint32_t)b << 16);
}
__device__ __forceinline__ uint32_t cvt_pk_bf16(float lo, float hi) {
    uint32_t r;
    asm("v_cvt_pk_bf16_f32 %0, %1, %2" : "=v"(r) : "v"(lo), "v"(hi));
    return r;
}

// async global->LDS, 16B per lane; LDS dest is wave-uniform base + lane*16.
#define GLL16(gp, lp) __builtin_amdgcn_global_load_lds( \
    (const __attribute__((address_space(1))) void*)(gp), \
    (__attribute__((address_space(3))) void*)(lp), 16, 0, 0)

// Pre-kernel: W [256][128] f32 -> Wt [128][256] bf16 (transposed, 64 KB, L2-hot).
__global__ void k_convW(const float* __restrict__ W, unsigned short* __restrict__ Wt) {
    int i = blockIdx.x * 256 + threadIdx.x;  // 32768 elements
    int k = i >> 7, c = i & 127;
    Wt[c * 256 + k] = f2bf(W[i]);
}

// GEMM: h = ns @ W via bf16 MFMA. 32 rows x 128 cols per block, 4 waves,
// wave w owns cols [w*32, w*32+32), mt in {0,1} covers the 32 rows.
// A staged as fp32 via global_load_lds (16B), granule-XOR swizzle applied on
// the GLOBAL source address (LDS dest must stay linear); fragment reads apply
// the same XOR and convert with v_cvt_pk_bf16_f32. B frags pinned in VGPRs.
// LDS 33 KB -> 4 blocks/CU (vs round-2's 2) to hide the staging latency.
__global__ __launch_bounds__(256, 3) void k_gemm(
    const float* __restrict__ ns, const unsigned short* __restrict__ Wt,
    const float* __restrict__ ka, unsigned short* __restrict__ hb,
    float* __restrict__ a_src, float* __restrict__ a_dst)
{
    __shared__ char smem[32 * 1024 + 1024];  // A fp32 [32][256] (reused as Ht) + ka
    float* ka_s = (float*)(smem + 32768);
    const int t = threadIdx.x;
    const int lane = t & 63;
    const int w = t >> 6;
    const int row0 = blockIdx.x * 32;        // 3125 * 32 = 100000 exact
    const int lrow = lane & 15;
    const int khalf = lane >> 4;

    ka_s[t] = ka[t];

    // ---- B fragments: bfrag[nt][ks], (lane,elem)->k = khalf*8 + ks*32 + e ----
    short8 bfrag[2][8];
    {
        const int col0 = w * 32 + lrow;
        #pragma unroll
        for (int nt = 0; nt < 2; ++nt) {
            const unsigned short* wp = Wt + (size_t)(col0 + nt * 16) * 256 + khalf * 8;
            #pragma unroll
            for (int ks = 0; ks < 8; ++ks)
                bfrag[nt][ks] = *(const short8*)(wp + ks * 32);
        }
    }
    #pragma unroll
    for (int nt = 0; nt < 2; ++nt)
        #pragma unroll
        for (int ks = 0; ks < 8; ++ks)
            asm volatile("" : "+v"(bfrag[nt][ks]));  // pin (round-3 lesson: VGPR=44 => resunk loads)

    // ---- Stage A: wave w writes rows [w*8, w*8+8), one 1KB row per issue.
    // LDS linear granule gL=lane holds global granule gL ^ (row&7).
    #pragma unroll
    for (int i = 0; i < 8; ++i) {
        const int r = w * 8 + i;
        const float* src = ns + (size_t)(row0 + r) * FF + ((lane ^ (r & 7)) * 4);
        GLL16(src, smem + r * 1024);
    }
    __syncthreads();

    // ---- K-loop: per ks, 4 swizzled b128 LDS reads + 8 cvt_pk + 4 MFMA ----
    f32x4 acc[2][2];
    #pragma unroll
    for (int mt = 0; mt < 2; ++mt)
        #pragma unroll
        for (int nt = 0; nt < 2; ++nt)
            acc[mt][nt] = (f32x4){0.f, 0.f, 0.f, 0.f};

    #pragma unroll
    for (int ks = 0; ks < 8; ++ks) {
        short8 a[2];
        #pragma unroll
        for (int mt = 0; mt < 2; ++mt) {
            const int row = mt * 16 + lrow;
            const int kg = ks * 8 + khalf * 2;      // k-granule (4 floats each)
            const char* rb = smem + row * 1024;
            f32x4 x0 = *(const f32x4*)(rb + ((kg ^ (row & 7)) * 16));
            f32x4 x1 = *(const f32x4*)(rb + (((kg + 1) ^ (row & 7)) * 16));
            uint4 u;
            u.x = cvt_pk_bf16(x0[0], x0[1]);
            u.y = cvt_pk_bf16(x0[2], x0[3]);
            u.z = cvt_pk_bf16(x1[0], x1[1]);
            u.w = cvt_pk_bf16(x1[2], x1[3]);
            a[mt] = __builtin_bit_cast(short8, u);
        }
        #pragma unroll
        for (int mt = 0; mt < 2; ++mt)
            #pragma unroll
            for (int nt = 0; nt < 2; ++nt)
                acc[mt][nt] = __builtin_amdgcn_mfma_f32_16x16x32_bf16(
                    a[mt], bfrag[nt][ks], acc[mt][nt], 0, 0, 0);
    }

    __syncthreads();  // A reads done; reuse smem as Ht[32][136] ushort

    // ---- acc -> Ht (stride 136 shorts) ----
    unsigned short* Hs = (unsigned short*)smem;
    {
        const int wcol = w * 32;
        #pragma unroll
        for (int mt = 0; mt < 2; ++mt)
            #pragma unroll
            for (int nt = 0; nt < 2; ++nt)
                #pragma unroll
                for (int r = 0; r < 4; ++r) {
                    int row = mt * 16 + khalf * 4 + r;
                    int col = wcol + nt * 16 + lrow;
                    Hs[row * 136 + col] = f2bf(acc[mt][nt][r]);
                }
    }
    __syncthreads();

    // ---- coalesced hb store + attention dots (8 threads per row, 16 dims each) ----
    {
        const int row = t >> 3, q8 = t & 7;
        const int gr = row0 + row;
        short8 hv0 = *(const short8*)(Hs + row * 136 + q8 * 16);
        short8 hv1 = *(const short8*)(Hs + row * 136 + q8 * 16 + 8);
        float ps = 0.f, pd = 0.f;
        #pragma unroll
        for (int e = 0; e < 8; ++e) {
            int c = q8 * 16 + e;
            ps = fmaf(bf2f((unsigned short)hv0[e]), ka_s[c], ps);
            pd = fmaf(bf2f((unsigned short)hv0[e]), ka_s[UU + c], pd);
            ps = fmaf(bf2f((unsigned short)hv1[e]), ka_s[c + 8], ps);
            pd = fmaf(bf2f((unsigned short)hv1[e]), ka_s[UU + c + 8], pd);
        }
        short8* op = (short8*)(hb + (size_t)gr * UU + q8 * 16);
        op[0] = hv0;
        op[1] = hv1;
        ps += __shfl_xor(ps, 1, 64); ps += __shfl_xor(ps, 2, 64); ps += __shfl_xor(ps, 4, 64);
        pd += __shfl_xor(pd, 1, 64); pd += __shfl_xor(pd, 2, 64); pd += __shfl_xor(pd, 4, 64);
        if (q8 == 0) { a_src[gr] = ps; a_dst[gr] = pd; }
    }
}

// Edge kernel: scores + per-node softmax -> packed nd[e] = (dst<<15) | norm_q15.
// 16 consecutive threads = one node (src sorted, exactly DEG=16 edges/node).
__global__ __launch_bounds__(256, 8) void k_edge(
    const int* __restrict__ edges, const float* __restrict__ ew,
    const float* __restrict__ a_src, const float* __restrict__ a_dst,
    uint32_t* __restrict__ nd)
{
    const int ei = blockIdx.x * 256 + threadIdx.x;
    const int n = ei >> 4;
    const int dst = edges[2 * ei + 1];
    const float w = ew[ei];
    const float x0 = w * (a_src[n] + a_dst[dst]);
    float x = x0 > 0.f ? x0 : 0.2f * x0;        // leaky_relu, slope 0.2
    x = fminf(2.f, fmaxf(-2.f, x));             // clip
    const float s = __expf(x);

    float ssum = s;                              // xor masks <16 stay in-group
    ssum += __shfl_xor(ssum, 1, 64);
    ssum += __shfl_xor(ssum, 2, 64);
    ssum += __shfl_xor(ssum, 4, 64);
    ssum += __shfl_xor(ssum, 8, 64);
    const float norm = s / ssum;

    uint32_t q15 = (uint32_t)(norm * 32768.f + 0.5f);
    if (q15 > 32767u) q15 = 32767u;
    nd[ei] = ((uint32_t)dst << 15) | q15;
}

// Aggregation: 4 nodes per wave, 16 lanes per node, lane q owns 16B (8 bf16
// dims) of the row. All 16 row-loads batched into registers (r[16]) so 16
// independent L2/L3 accesses are in flight per lane (round-2 post-mortem:
// VGPR=32 serialized them). Full-row 256B gather per edge, full-row 512B
// coalesced f32 output write per node.
__global__ __launch_bounds__(256, 4) void k_agg(
    const uint32_t* __restrict__ nd, const unsigned short* __restrict__ hb,
    float* __restrict__ out)
{
    const int t = threadIdx.x;
    const int lane = t & 63;
    const int wv = t >> 6;
    const int g = lane >> 4;
    const int q = lane & 15;
    const int n = blockIdx.x * 16 + wv * 4 + g;   // 6250*16 = 100000 exact

    const uint32_t v = nd[(size_t)n * DEG + q];   // this lane's edge
    const uint32_t dstB = (v >> 15) << 8;         // dst * 256 bytes
    const float normf = (float)(v & 32767u) * (1.f / 32768.f);
    const int gb = lane & 48;

    // addresses for all 16 edges of this node
    uint32_t ab[16];
    #pragma unroll
    for (int j = 0; j < 16; ++j) ab[j] = __shfl(dstB, gb | j, 64);

    // batch-issue 16 independent 16B gathers
    const char* hbase = (const char*)hb + q * 16;
    uint4 r[16];
    #pragma unroll
    for (int j = 0; j < 16; ++j) r[j] = *(const uint4*)(hbase + ab[j]);

    float nf[16];
    #pragma unroll
    for (int j = 0; j < 16; ++j) nf[j] = __shfl(normf, gb | j, 64);

    float acc[8];
    #pragma unroll
    for (int d = 0; d < 8; ++d) acc[d] = 0.f;
    #pragma unroll
    for (int j = 0; j < 16; ++j) {
        acc[0] = fmaf(nf[j], __builtin_bit_cast(float, r[j].x << 16), acc[0]);
        acc[1] = fmaf(nf[j], __builtin_bit_cast(float, r[j].x & 0xffff0000u), acc[1]);
        acc[2] = fmaf(nf[j], __builtin_bit_cast(float, r[j].y << 16), acc[2]);
        acc[3] = fmaf(nf[j], __builtin_bit_cast(float, r[j].y & 0xffff0000u), acc[3]);
        acc[4] = fmaf(nf[j], __builtin_bit_cast(float, r[j].z << 16), acc[4]);
        acc[5] = fmaf(nf[j], __builtin_bit_cast(float, r[j].z & 0xffff0000u), acc[5]);
        acc[6] = fmaf(nf[j], __builtin_bit_cast(float, r[j].w << 16), acc[6]);
        acc[7] = fmaf(nf[j], __builtin_bit_cast(float, r[j].w & 0xffff0000u), acc[7]);
    }

    float* op = out + (size_t)n * UU + q * 8;
    float4 o0, o1;
    o0.x = acc[0]; o0.y = acc[1]; o0.z = acc[2]; o0.w = acc[3];
    o1.x = acc[4]; o1.y = acc[5]; o1.z = acc[6]; o1.w = acc[7];
    *(float4*)op = o0;
    *(float4*)(op + 4) = o1;
}

extern "C" void kernel_launch(void* const* d_in, const int* in_sizes, int n_in,
                              void* d_out, int out_size, void* d_ws, size_t ws_size,
                              hipStream_t stream) {
    const float* ns    = (const float*)d_in[0];  // [1, N, 256] f32
    const int*   edges = (const int*)d_in[1];    // [1, E, 2] i32, src sorted
    const float* ew    = (const float*)d_in[2];  // [1, E] f32
    const float* W     = (const float*)d_in[3];  // [256, 128] f32
    const float* ka    = (const float*)d_in[4];  // [256, 1] f32
    float* out = (float*)d_out;                  // [N, 128] f32

    char* ws = (char*)d_ws;
    unsigned short* hb = (unsigned short*)ws;                    // N*128 bf16 = 25.6 MB
    float* a_src = (float*)(ws + (size_t)NN * UU * 2);           // N f32
    float* a_dst = a_src + NN;                                   // N f32
    unsigned short* Wt = (unsigned short*)(ws + (size_t)NN * UU * 2 + 2 * (size_t)NN * 4);  // 64 KB
    uint32_t* nd = (uint32_t*)(ws + (size_t)NN * UU * 2 + 2 * (size_t)NN * 4 + 65536);      // E u32 = 6.4 MB

    k_convW<<<FF * UU / 256, 256, 0, stream>>>(W, Wt);                        // 128 blocks
    k_gemm<<<NN / 32, 256, 0, stream>>>(ns, Wt, ka, hb, a_src, a_dst);        // 3125 blocks
    k_edge<<<NN * DEG / 256, 256, 0, stream>>>(edges, ew, a_src, a_dst, nd);  // 6250 blocks
    k_agg<<<NN / 16, 256, 0, stream>>>(nd, hb, out);                          // 6250 blocks
}